// Round 13
// baseline (1083.113 us; speedup 1.0000x reference)
//
#include <hip/hip_runtime.h>
#include <hip/hip_bf16.h>
#include <stdint.h>

#define N_EMBD    256
#define N_INPUTS  66
#define N_LEVELS  8
#define APL       4096
#define NPL       2048
#define LVL       6144
#define N_HID     1024

typedef __hip_bfloat16 bf16;
typedef __attribute__((ext_vector_type(8))) short short8;
typedef __attribute__((ext_vector_type(4))) float f32x4;

static __device__ __forceinline__ unsigned short f2b(float f) {
  bf16 h = __float2bfloat16(f);
  return *reinterpret_cast<unsigned short*>(&h);
}

// ---------------- input copy: rows 0..65 of node table ----------------
__global__ void k_copy_inputs(const float* __restrict__ in, float* __restrict__ out) {
  int r = blockIdx.x, t = threadIdx.x;  // 66 blocks x 64 threads
  ((float4*)(out + (size_t)r * 256))[t] = ((const float4*)(in + (size_t)r * 256))[t];
}

// ---------------- ALL weight transposes in ONE dispatch ----------------
__global__ void k_transpose_all(const float* __restrict__ W_in, const float* __restrict__ W_hid,
                                const float* __restrict__ W_out,
                                bf16* __restrict__ WtIn, bf16* __restrict__ WtHid,
                                bf16* __restrict__ WtOut) {
  __shared__ float t[32][33];
  int z = blockIdx.z;
  const float* in; bf16* out; int K, N;
  if (z == 0)      { in = W_in;  out = WtIn;  K = 512;  N = 1024; }
  else if (z <= 8) { in = W_hid + (size_t)(z - 1) * 1024 * 1024; out = WtHid + (size_t)(z - 1) * 1024 * 1024; K = 1024; N = 1024; }
  else             { in = W_out; out = WtOut; K = 1024; N = 256; }
  int n0 = blockIdx.x * 32, k0 = blockIdx.y * 32;
  if (n0 >= N || k0 >= K) return;
  int tx = threadIdx.x, ty = threadIdx.y;
  #pragma unroll
  for (int j = 0; j < 32; j += 8)
    t[ty + j][tx] = in[(size_t)(k0 + ty + j) * N + n0 + tx];
  __syncthreads();
  #pragma unroll
  for (int j = 0; j < 32; j += 8)
    out[(size_t)(n0 + ty + j) * K + k0 + tx] = __float2bfloat16(t[tx][ty + j]);
}

// ---------------- fused NOT + gather, 256-thread blocks (4 items each) ----------------
__global__ void k_not_gather(const int* __restrict__ xe, const int* __restrict__ ye,
                             float* __restrict__ node, bf16* __restrict__ H0, int s) {
  int t = threadIdx.x & 63;
  int b = blockIdx.x * 4 + (threadIdx.x >> 6);  // 0..6143
  if (b < NPL) {
    int dst = s + APL + b;
    int src = xe[dst];
    float4 v = ((const float4*)(node + (size_t)src * 256))[t];
    float4 o; o.x = -v.x; o.y = -v.y; o.z = -v.z; o.w = -v.w;
    ((float4*)(node + (size_t)dst * 256))[t] = o;
  } else {
    int r = b - NPL;
    int xa = xe[s + r], ya = ye[s + r];
    float4 vx = ((const float4*)(node + (size_t)xa * 256))[t];
    float4 vy = ((const float4*)(node + (size_t)ya * 256))[t];
    ushort4 ox, oy;
    ox.x = f2b(vx.x); ox.y = f2b(vx.y); ox.z = f2b(vx.z); ox.w = f2b(vx.w);
    oy.x = f2b(vy.x); oy.y = f2b(vy.y); oy.z = f2b(vy.z); oy.w = f2b(vy.w);
    bf16* hr = H0 + (size_t)r * 512;
    ((ushort4*)hr)[t] = ox;
    ((ushort4*)(hr + 256))[t] = oy;
  }
}

// ---------------- BIG GEMM: 128x128 tile, 4 waves (64x64 each), mfma 16x16x32 ----------------
// LDS-traffic-minimal wave shape (45.7 B/MFLOP vs 68.6 at 64x32 waves).
// 4 LDS buffers (128KB), 3-deep counted-vmcnt pipeline, stage issued right after the
// entry barrier into the buffer freed 2 barriers ago (race-safe). Unroll-by-4,
// compile-time buffer selects. vmcnt: steady 16 (2x8 newer loads), tail 8 -> 0.
// Same MFMA K-order as prior rounds -> bit-identical output.
template<bool RELU, bool BF16OUT>
__global__ __launch_bounds__(256, 1)
void k_gemm128(const bf16* __restrict__ A, const bf16* __restrict__ Bt,
               const float* __restrict__ bias, void* __restrict__ Cout,
               int M, int N, int K) {
  constexpr int MT = 4, NT = 4, AIT = 4, BIT = 4;
  constexpr int ABYTES = 128 * 128;      // A tile: 128 rows x 64 bf16 = 16 KB
  constexpr int BUF = 2 * ABYTES;        // A + B = 32 KB
  __shared__ __align__(16) char smem[4 * BUF];  // 128 KB

  const int tid  = threadIdx.x;
  const int lane = tid & 63;
  const int w    = tid >> 6;
  const int wm   = w >> 1, wn = w & 1;
  const int m0 = blockIdx.x * 128;
  const int n0 = blockIdx.y * 128;

  // running global source pointers (swizzled), advanced +64 per STAGE
  const bf16* gA[AIT];
  const bf16* gB[BIT];
  #pragma unroll
  for (int it = 0; it < AIT; ++it) {
    int ci = it * 256 + tid;
    int r = ci >> 3, g = ci & 7, gs = g ^ (r & 7);
    gA[it] = A + (size_t)(m0 + r) * K + gs * 8;
  }
  #pragma unroll
  for (int it = 0; it < BIT; ++it) {
    int ci = it * 256 + tid;
    int r = ci >> 3, g = ci & 7, gs = g ^ (r & 7);
    gB[it] = Bt + (size_t)(n0 + r) * K + gs * 8;
  }

  // precomputed swizzled ds_read byte offsets
  int aoff[2][MT], boff[2][NT];
  #pragma unroll
  for (int kk = 0; kk < 2; ++kk) {
    #pragma unroll
    for (int mt = 0; mt < MT; ++mt) {
      int row = wm * 64 + mt * 16 + (lane & 15);
      int g = kk * 4 + (lane >> 4);
      aoff[kk][mt] = row * 128 + ((g ^ (row & 7)) * 16);
    }
    #pragma unroll
    for (int nt = 0; nt < NT; ++nt) {
      int row = wn * 64 + nt * 16 + (lane & 15);
      int g = kk * 4 + (lane >> 4);
      boff[kk][nt] = ABYTES + row * 128 + ((g ^ (row & 7)) * 16);
    }
  }

  f32x4 acc[MT][NT] = {};

  auto STAGE = [&](auto bufsel) {
    constexpr int BS = decltype(bufsel)::value;
    char* sA = smem + BS * BUF;
    char* sB = sA + ABYTES;
    #pragma unroll
    for (int it = 0; it < AIT; ++it) {
      __builtin_amdgcn_global_load_lds((const __attribute__((address_space(1))) void*)gA[it],
                                       (__attribute__((address_space(3))) void*)(sA + (it * 256 + w * 64) * 16),
                                       16, 0, 0);
      gA[it] += 64;
    }
    #pragma unroll
    for (int it = 0; it < BIT; ++it) {
      __builtin_amdgcn_global_load_lds((const __attribute__((address_space(1))) void*)gB[it],
                                       (__attribute__((address_space(3))) void*)(sB + (it * 256 + w * 64) * 16),
                                       16, 0, 0);
      gB[it] += 64;
    }
  };

  auto COMPUTE = [&](auto bufsel) {
    constexpr int BS = decltype(bufsel)::value;
    char* base = smem + BS * BUF;
    #pragma unroll
    for (int kk = 0; kk < 2; ++kk) {
      short8 af[MT], bfr[NT];
      #pragma unroll
      for (int mt = 0; mt < MT; ++mt)
        af[mt] = *(const short8*)(base + aoff[kk][mt]);
      #pragma unroll
      for (int nt = 0; nt < NT; ++nt)
        bfr[nt] = *(const short8*)(base + boff[kk][nt]);
      #pragma unroll
      for (int mt = 0; mt < MT; ++mt)
        #pragma unroll
        for (int nt = 0; nt < NT; ++nt)
          acc[mt][nt] = __builtin_amdgcn_mfma_f32_16x16x32_bf16(af[mt], bfr[nt], acc[mt][nt], 0, 0, 0);
    }
  };

  constexpr auto B0 = std::integral_constant<int, 0>{};
  constexpr auto B1 = std::integral_constant<int, 1>{};
  constexpr auto B2 = std::integral_constant<int, 2>{};
  constexpr auto B3 = std::integral_constant<int, 3>{};

  const int nK = K >> 6;  // 8 or 16: divisible by 4

  auto SUBSTEP = [&](int t, auto cbuf, auto sbuf) {
    int rem = nK - 1 - t;
    if (rem >= 2)      asm volatile("s_waitcnt vmcnt(16)" ::: "memory");
    else if (rem == 1) asm volatile("s_waitcnt vmcnt(8)" ::: "memory");
    else               asm volatile("s_waitcnt vmcnt(0)" ::: "memory");
    __builtin_amdgcn_s_barrier();          // all waves: batch t landed
    if (t + 3 < nK) STAGE(sbuf);           // into buffer freed 2 barriers ago
    COMPUTE(cbuf);
    __builtin_amdgcn_s_barrier();          // all waves done reading cbuf
  };

  STAGE(B0); STAGE(B1); STAGE(B2);         // batches 0,1,2

  for (int t4 = 0; t4 < nK; t4 += 4) {
    SUBSTEP(t4 + 0, B0, B3);
    SUBSTEP(t4 + 1, B1, B0);
    SUBSTEP(t4 + 2, B2, B1);
    SUBSTEP(t4 + 3, B3, B2);
  }

  // epilogue: bias + optional relu
  #pragma unroll
  for (int nt = 0; nt < NT; ++nt) {
    int col = n0 + wn * 64 + nt * 16 + (lane & 15);
    float bv = bias[col];
    #pragma unroll
    for (int mt = 0; mt < MT; ++mt) {
      int rbase = m0 + wm * 64 + mt * 16 + (lane >> 4) * 4;
      #pragma unroll
      for (int r = 0; r < 4; ++r) {
        float v = acc[mt][nt][r] + bv;
        if (RELU) v = fmaxf(v, 0.f);
        if (BF16OUT)
          ((unsigned short*)Cout)[(size_t)(rbase + r) * N + col] = f2b(v);
        else
          ((float*)Cout)[(size_t)(rbase + r) * N + col] = v;
      }
    }
  }
}

// ---------------- small GEMM (out layer): R7 proven 64x64 structure ----------------
template<int BM, int BN, bool RELU, bool BF16OUT>
__global__ __launch_bounds__(256, 2)
void k_gemm(const bf16* __restrict__ A, const bf16* __restrict__ Bt,
            const float* __restrict__ bias, void* __restrict__ Cout,
            int M, int N, int K) {
  constexpr int MT = BM / 32;
  constexpr int NT = BN / 32;
  constexpr int AIT = BM / 32;
  constexpr int BIT = BN / 32;
  constexpr int ABYTES = BM * 128;
  constexpr int BBYTES = BN * 128;
  constexpr int BUF = ABYTES + BBYTES;
  constexpr int LOADS = AIT + BIT;
  __shared__ __align__(16) char smem[2 * BUF];

  const int tid  = threadIdx.x;
  const int lane = tid & 63;
  const int w    = tid >> 6;
  const int wm   = w >> 1, wn = w & 1;
  const int m0 = blockIdx.x * BM;
  const int n0 = blockIdx.y * BN;

  const bf16* gA[AIT];
  const bf16* gB[BIT];
  #pragma unroll
  for (int it = 0; it < AIT; ++it) {
    int ci = it * 256 + tid;
    int r = ci >> 3, g = ci & 7, gs = g ^ (r & 7);
    gA[it] = A + (size_t)(m0 + r) * K + gs * 8;
  }
  #pragma unroll
  for (int it = 0; it < BIT; ++it) {
    int ci = it * 256 + tid;
    int r = ci >> 3, g = ci & 7, gs = g ^ (r & 7);
    gB[it] = Bt + (size_t)(n0 + r) * K + gs * 8;
  }

  int aoff[2][MT], boff[2][NT];
  #pragma unroll
  for (int kk = 0; kk < 2; ++kk) {
    #pragma unroll
    for (int mt = 0; mt < MT; ++mt) {
      int row = wm * (BM / 2) + mt * 16 + (lane & 15);
      int g = kk * 4 + (lane >> 4);
      aoff[kk][mt] = row * 128 + ((g ^ (row & 7)) * 16);
    }
    #pragma unroll
    for (int nt = 0; nt < NT; ++nt) {
      int row = wn * (BN / 2) + nt * 16 + (lane & 15);
      int g = kk * 4 + (lane >> 4);
      boff[kk][nt] = ABYTES + row * 128 + ((g ^ (row & 7)) * 16);
    }
  }

  f32x4 acc[MT][NT] = {};

  auto STAGE = [&](auto bufsel) {
    constexpr int BS = decltype(bufsel)::value;
    char* sA = smem + BS * BUF;
    char* sB = sA + ABYTES;
    #pragma unroll
    for (int it = 0; it < AIT; ++it) {
      __builtin_amdgcn_global_load_lds((const __attribute__((address_space(1))) void*)gA[it],
                                       (__attribute__((address_space(3))) void*)(sA + (it * 256 + w * 64) * 16),
                                       16, 0, 0);
      gA[it] += 64;
    }
    #pragma unroll
    for (int it = 0; it < BIT; ++it) {
      __builtin_amdgcn_global_load_lds((const __attribute__((address_space(1))) void*)gB[it],
                                       (__attribute__((address_space(3))) void*)(sB + (it * 256 + w * 64) * 16),
                                       16, 0, 0);
      gB[it] += 64;
    }
  };

  auto COMPUTE = [&](auto bufsel) {
    constexpr int BS = decltype(bufsel)::value;
    char* base = smem + BS * BUF;
    #pragma unroll
    for (int kk = 0; kk < 2; ++kk) {
      short8 af[MT], bfr[NT];
      #pragma unroll
      for (int mt = 0; mt < MT; ++mt)
        af[mt] = *(const short8*)(base + aoff[kk][mt]);
      #pragma unroll
      for (int nt = 0; nt < NT; ++nt)
        bfr[nt] = *(const short8*)(base + boff[kk][nt]);
      #pragma unroll
      for (int mt = 0; mt < MT; ++mt)
        #pragma unroll
        for (int nt = 0; nt < NT; ++nt)
          acc[mt][nt] = __builtin_amdgcn_mfma_f32_16x16x32_bf16(af[mt], bfr[nt], acc[mt][nt], 0, 0, 0);
    }
  };

  auto WAITC = [&](auto n) {
    constexpr int NW = decltype(n)::value;
    if constexpr (NW == 6)      asm volatile("s_waitcnt vmcnt(6)" ::: "memory");
    else if constexpr (NW == 4) asm volatile("s_waitcnt vmcnt(4)" ::: "memory");
    else                        asm volatile("s_waitcnt vmcnt(0)" ::: "memory");
  };
  constexpr auto C0 = std::integral_constant<int, 0>{};
  constexpr auto C1 = std::integral_constant<int, 1>{};
  constexpr auto CL = std::integral_constant<int, LOADS>{};

  const int nK = K >> 6;
  STAGE(C0);
  STAGE(C1);

  for (int ks2 = 0; ks2 < nK; ks2 += 2) {
    WAITC(CL);
    __builtin_amdgcn_s_barrier();
    COMPUTE(C0);
    __builtin_amdgcn_s_barrier();
    if (ks2 + 2 < nK) STAGE(C0);

    if (ks2 + 2 < nK) WAITC(CL); else WAITC(C0);
    __builtin_amdgcn_s_barrier();
    COMPUTE(C1);
    __builtin_amdgcn_s_barrier();
    if (ks2 + 3 < nK) STAGE(C1);
  }

  #pragma unroll
  for (int nt = 0; nt < NT; ++nt) {
    int col = n0 + wn * (BN / 2) + nt * 16 + (lane & 15);
    float bv = bias[col];
    #pragma unroll
    for (int mt = 0; mt < MT; ++mt) {
      int rbase = m0 + wm * (BM / 2) + mt * 16 + (lane >> 4) * 4;
      #pragma unroll
      for (int r = 0; r < 4; ++r) {
        float v = acc[mt][nt][r] + bv;
        if (RELU) v = fmaxf(v, 0.f);
        if (BF16OUT)
          ((unsigned short*)Cout)[(size_t)(rbase + r) * N + col] = f2b(v);
        else
          ((float*)Cout)[(size_t)(rbase + r) * N + col] = v;
      }
    }
  }
}

// ---------------- LayerNorm, 256-thread blocks (4 rows each) ----------------
__global__ void k_ln(const float* __restrict__ X, const float* __restrict__ g,
                     const float* __restrict__ b, float* __restrict__ node, int s) {
  int t = threadIdx.x & 63;
  int r = blockIdx.x * 4 + (threadIdx.x >> 6);  // 0..4095
  float4 x = ((const float4*)(X + (size_t)r * 256))[t];
  float sm = x.x + x.y + x.z + x.w;
  float sq = x.x * x.x + x.y * x.y + x.z * x.z + x.w * x.w;
  #pragma unroll
  for (int o = 1; o < 64; o <<= 1) { sm += __shfl_xor(sm, o); sq += __shfl_xor(sq, o); }
  float mu  = sm * (1.f / 256.f);
  float var = sq * (1.f / 256.f) - mu * mu;
  float rs  = rsqrtf(var + 1e-5f);
  float4 gv = ((const float4*)g)[t], bv = ((const float4*)b)[t];
  float4 o4;
  o4.x = (x.x - mu) * rs * gv.x + bv.x;
  o4.y = (x.y - mu) * rs * gv.y + bv.y;
  o4.z = (x.z - mu) * rs * gv.z + bv.z;
  o4.w = (x.w - mu) * rs * gv.w + bv.w;
  ((float4*)(node + (size_t)(s + r) * 256))[t] = o4;
}

extern "C" void kernel_launch(void* const* d_in, const int* in_sizes, int n_in,
                              void* d_out, int out_size, void* d_ws, size_t ws_size,
                              hipStream_t stream) {
  const int*   x_edges    = (const int*)d_in[1];
  const int*   y_edges    = (const int*)d_in[2];
  const float* input_embd = (const float*)d_in[3];
  const float* W_in       = (const float*)d_in[4];
  const float* b_in       = (const float*)d_in[5];
  const float* W_hid      = (const float*)d_in[6];
  const float* b_hid      = (const float*)d_in[7];
  const float* W_out      = (const float*)d_in[8];
  const float* b_out      = (const float*)d_in[9];
  const float* ln_g       = (const float*)d_in[10];
  const float* ln_b       = (const float*)d_in[11];
  float* node = (float*)d_out;

  char* ws = (char*)d_ws;
  bf16* WtIn  = (bf16*)(ws);                                   // 1024x512
  bf16* WtHid = (bf16*)(ws + (size_t)1048576);                 // 8x1024x1024
  bf16* WtOut = (bf16*)(ws + (size_t)17825792);                // 256x1024
  bf16* H0    = (bf16*)(ws + (size_t)18350080);                // 4096x512
  bf16* HA    = (bf16*)(ws + (size_t)22544384);                // 4096x1024
  bf16* HB    = (bf16*)(ws + (size_t)30932992);                // 4096x1024
  float* OutF = (float*)HB;                                    // reuse (4096x256 f32)

  // node rows 0..65 = input embeddings
  k_copy_inputs<<<dim3(66), dim3(64), 0, stream>>>(input_embd, node);

  // all weight transposes in one dispatch
  k_transpose_all<<<dim3(32, 32, 10), dim3(32, 8), 0, stream>>>(W_in, W_hid, W_out, WtIn, WtHid, WtOut);

  for (int l = 0; l < N_LEVELS; ++l) {
    int s = N_INPUTS + l * LVL;
    k_not_gather<<<dim3((NPL + APL) / 4), dim3(256), 0, stream>>>(x_edges, y_edges, node, H0, s);

    // MLP: 128x128 tiles (64x64 waves), 4-buffer 3-deep pipeline
    k_gemm128<true, true><<<dim3(32, 8), dim3(256), 0, stream>>>(H0, WtIn, b_in, HA, 4096, 1024, 512);
    const bf16* src = HA; bf16* dst = HB;
    for (int i = 0; i < 8; ++i) {
      k_gemm128<true, true><<<dim3(32, 8), dim3(256), 0, stream>>>(
          src, WtHid + (size_t)i * 1024 * 1024, b_hid + i * 1024, dst, 4096, 1024, 1024);
      const bf16* tmp = src; src = dst; dst = (bf16*)tmp;
    }
    // src == HA here; fp32 MLP output into OutF (= HB space, no longer needed)
    k_gemm<64, 64, false, false><<<dim3(64, 4), dim3(256), 0, stream>>>(src, WtOut, b_out, OutF, 4096, 256, 1024);

    k_ln<<<dim3(APL / 4), dim3(256), 0, stream>>>(OutF, ln_g, ln_b, node, s);
  }
}

// Round 14
// 1079.499 us; speedup vs baseline: 1.0033x; 1.0033x over previous
//
#include <hip/hip_runtime.h>
#include <hip/hip_bf16.h>
#include <stdint.h>

#define N_EMBD    256
#define N_INPUTS  66
#define N_LEVELS  8
#define APL       4096
#define NPL       2048
#define LVL       6144
#define N_HID     1024

typedef __hip_bfloat16 bf16;
typedef __attribute__((ext_vector_type(8))) short short8;
typedef __attribute__((ext_vector_type(4))) float f32x4;

static __device__ __forceinline__ unsigned short f2b(float f) {
  bf16 h = __float2bfloat16(f);
  return *reinterpret_cast<unsigned short*>(&h);
}

// ---------------- input copy: rows 0..65 of node table ----------------
__global__ void k_copy_inputs(const float* __restrict__ in, float* __restrict__ out) {
  int r = blockIdx.x, t = threadIdx.x;  // 66 blocks x 64 threads
  ((float4*)(out + (size_t)r * 256))[t] = ((const float4*)(in + (size_t)r * 256))[t];
}

// ---------------- ALL weight transposes in ONE dispatch ----------------
__global__ void k_transpose_all(const float* __restrict__ W_in, const float* __restrict__ W_hid,
                                const float* __restrict__ W_out,
                                bf16* __restrict__ WtIn, bf16* __restrict__ WtHid,
                                bf16* __restrict__ WtOut) {
  __shared__ float t[32][33];
  int z = blockIdx.z;
  const float* in; bf16* out; int K, N;
  if (z == 0)      { in = W_in;  out = WtIn;  K = 512;  N = 1024; }
  else if (z <= 8) { in = W_hid + (size_t)(z - 1) * 1024 * 1024; out = WtHid + (size_t)(z - 1) * 1024 * 1024; K = 1024; N = 1024; }
  else             { in = W_out; out = WtOut; K = 1024; N = 256; }
  int n0 = blockIdx.x * 32, k0 = blockIdx.y * 32;
  if (n0 >= N || k0 >= K) return;
  int tx = threadIdx.x, ty = threadIdx.y;
  #pragma unroll
  for (int j = 0; j < 32; j += 8)
    t[ty + j][tx] = in[(size_t)(k0 + ty + j) * N + n0 + tx];
  __syncthreads();
  #pragma unroll
  for (int j = 0; j < 32; j += 8)
    out[(size_t)(n0 + ty + j) * K + k0 + tx] = __float2bfloat16(t[tx][ty + j]);
}

// ---------------- fused NOT + gather, 256-thread blocks (4 items each) ----------------
__global__ void k_not_gather(const int* __restrict__ xe, const int* __restrict__ ye,
                             float* __restrict__ node, bf16* __restrict__ H0, int s) {
  int t = threadIdx.x & 63;
  int b = blockIdx.x * 4 + (threadIdx.x >> 6);  // 0..6143
  if (b < NPL) {
    int dst = s + APL + b;
    int src = xe[dst];
    float4 v = ((const float4*)(node + (size_t)src * 256))[t];
    float4 o; o.x = -v.x; o.y = -v.y; o.z = -v.z; o.w = -v.w;
    ((float4*)(node + (size_t)dst * 256))[t] = o;
  } else {
    int r = b - NPL;
    int xa = xe[s + r], ya = ye[s + r];
    float4 vx = ((const float4*)(node + (size_t)xa * 256))[t];
    float4 vy = ((const float4*)(node + (size_t)ya * 256))[t];
    ushort4 ox, oy;
    ox.x = f2b(vx.x); ox.y = f2b(vx.y); ox.z = f2b(vx.z); ox.w = f2b(vx.w);
    oy.x = f2b(vy.x); oy.y = f2b(vy.y); oy.z = f2b(vy.z); oy.w = f2b(vy.w);
    bf16* hr = H0 + (size_t)r * 512;
    ((ushort4*)hr)[t] = ox;
    ((ushort4*)(hr + 256))[t] = oy;
  }
}

// ---------------- GEMM: C = act(A[MxK] @ B[KxN] + bias), Bt[N][K] ----------------
// R7/R12 proven structure: BK=64, 4 waves (2x2), wave (BM/2)x(BN/2), mfma 16x16x32,
// 2-deep counted-vmcnt pipeline, 2x-unrolled K-loop, compile-time buffer selects,
// precomputed ds_read offsets, running global pointers.
// NEW: MINW template param -> 64x64 tiles run at 4 blocks/CU (TLP probe).
// global_load_lds width 16, XOR-swizzle on global SOURCE + on ds_read (rule #21).
template<int BM, int BN, int MINW, bool RELU, bool BF16OUT>
__global__ __launch_bounds__(256, MINW)
void k_gemm(const bf16* __restrict__ A, const bf16* __restrict__ Bt,
            const float* __restrict__ bias, void* __restrict__ Cout,
            int M, int N, int K) {
  constexpr int MT = BM / 32;            // A-frags per wave (wave owns BM/2 rows)
  constexpr int NT = BN / 32;
  constexpr int AIT = BM / 32;           // A-load iters per STAGE
  constexpr int BIT = BN / 32;
  constexpr int ABYTES = BM * 128;       // BM rows x 64 bf16
  constexpr int BBYTES = BN * 128;
  constexpr int BUF = ABYTES + BBYTES;
  constexpr int LOADS = AIT + BIT;       // global_load_lds per thread per STAGE
  __shared__ __align__(16) char smem[2 * BUF];

  const int tid  = threadIdx.x;
  const int lane = tid & 63;
  const int w    = tid >> 6;
  const int wm   = w >> 1, wn = w & 1;
  const int m0 = blockIdx.x * BM;
  const int n0 = blockIdx.y * BN;

  // ---- running global source pointers (swizzled), advanced +64 per STAGE ----
  const bf16* gA[AIT];
  const bf16* gB[BIT];
  #pragma unroll
  for (int it = 0; it < AIT; ++it) {
    int ci = it * 256 + tid;
    int r = ci >> 3, g = ci & 7, gs = g ^ (r & 7);
    gA[it] = A + (size_t)(m0 + r) * K + gs * 8;
  }
  #pragma unroll
  for (int it = 0; it < BIT; ++it) {
    int ci = it * 256 + tid;
    int r = ci >> 3, g = ci & 7, gs = g ^ (r & 7);
    gB[it] = Bt + (size_t)(n0 + r) * K + gs * 8;
  }

  // ---- precomputed swizzled ds_read byte offsets (buffer-relative) ----
  int aoff[2][MT], boff[2][NT];
  #pragma unroll
  for (int kk = 0; kk < 2; ++kk) {
    #pragma unroll
    for (int mt = 0; mt < MT; ++mt) {
      int row = wm * (BM / 2) + mt * 16 + (lane & 15);
      int g = kk * 4 + (lane >> 4);
      aoff[kk][mt] = row * 128 + ((g ^ (row & 7)) * 16);
    }
    #pragma unroll
    for (int nt = 0; nt < NT; ++nt) {
      int row = wn * (BN / 2) + nt * 16 + (lane & 15);
      int g = kk * 4 + (lane >> 4);
      boff[kk][nt] = ABYTES + row * 128 + ((g ^ (row & 7)) * 16);
    }
  }

  f32x4 acc[MT][NT] = {};

  auto STAGE = [&](auto bufsel) {  // bufsel: integral_constant<int,0|1>
    constexpr int BS = decltype(bufsel)::value;
    char* sA = smem + BS * BUF;
    char* sB = sA + ABYTES;
    #pragma unroll
    for (int it = 0; it < AIT; ++it) {
      __builtin_amdgcn_global_load_lds((const __attribute__((address_space(1))) void*)gA[it],
                                       (__attribute__((address_space(3))) void*)(sA + (it * 256 + w * 64) * 16),
                                       16, 0, 0);
      gA[it] += 64;
    }
    #pragma unroll
    for (int it = 0; it < BIT; ++it) {
      __builtin_amdgcn_global_load_lds((const __attribute__((address_space(1))) void*)gB[it],
                                       (__attribute__((address_space(3))) void*)(sB + (it * 256 + w * 64) * 16),
                                       16, 0, 0);
      gB[it] += 64;
    }
  };

  auto COMPUTE = [&](auto bufsel) {
    constexpr int BS = decltype(bufsel)::value;
    char* base = smem + BS * BUF;
    #pragma unroll
    for (int kk = 0; kk < 2; ++kk) {
      short8 af[MT], bfr[NT];
      #pragma unroll
      for (int mt = 0; mt < MT; ++mt)
        af[mt] = *(const short8*)(base + aoff[kk][mt]);
      #pragma unroll
      for (int nt = 0; nt < NT; ++nt)
        bfr[nt] = *(const short8*)(base + boff[kk][nt]);
      #pragma unroll
      for (int mt = 0; mt < MT; ++mt)
        #pragma unroll
        for (int nt = 0; nt < NT; ++nt)
          acc[mt][nt] = __builtin_amdgcn_mfma_f32_16x16x32_bf16(af[mt], bfr[nt], acc[mt][nt], 0, 0, 0);
    }
  };

  auto WAITC = [&](auto n) {
    constexpr int NW = decltype(n)::value;
    if constexpr (NW == 6)      asm volatile("s_waitcnt vmcnt(6)" ::: "memory");
    else if constexpr (NW == 4) asm volatile("s_waitcnt vmcnt(4)" ::: "memory");
    else                        asm volatile("s_waitcnt vmcnt(0)" ::: "memory");
  };
  constexpr auto C0 = std::integral_constant<int, 0>{};
  constexpr auto C1 = std::integral_constant<int, 1>{};
  constexpr auto CL = std::integral_constant<int, LOADS>{};

  const int nK = K >> 6;  // 8 or 16 here: even, >= 2
  STAGE(C0);
  STAGE(C1);

  for (int ks2 = 0; ks2 < nK; ks2 += 2) {
    // --- step A: compute tile ks2 from buf0; batches {ks2, ks2+1} outstanding ---
    WAITC(CL);                       // batch ks2 landed, ks2+1 stays in flight
    __builtin_amdgcn_s_barrier();
    COMPUTE(C0);
    __builtin_amdgcn_s_barrier();
    if (ks2 + 2 < nK) STAGE(C0);     // issue batch ks2+2 into buf0

    // --- step B: compute tile ks2+1 from buf1 ---
    if (ks2 + 2 < nK) WAITC(CL); else WAITC(C0);
    __builtin_amdgcn_s_barrier();
    COMPUTE(C1);
    __builtin_amdgcn_s_barrier();
    if (ks2 + 3 < nK) STAGE(C1);     // issue batch ks2+3 into buf1
  }

  // epilogue: bias + optional relu, bf16 or fp32 store
  #pragma unroll
  for (int nt = 0; nt < NT; ++nt) {
    int col = n0 + wn * (BN / 2) + nt * 16 + (lane & 15);
    float bv = bias[col];
    #pragma unroll
    for (int mt = 0; mt < MT; ++mt) {
      int rbase = m0 + wm * (BM / 2) + mt * 16 + (lane >> 4) * 4;
      #pragma unroll
      for (int r = 0; r < 4; ++r) {
        float v = acc[mt][nt][r] + bv;
        if (RELU) v = fmaxf(v, 0.f);
        if (BF16OUT)
          ((unsigned short*)Cout)[(size_t)(rbase + r) * N + col] = f2b(v);
        else
          ((float*)Cout)[(size_t)(rbase + r) * N + col] = v;
      }
    }
  }
}

// ---------------- LayerNorm, 256-thread blocks (4 rows each) ----------------
__global__ void k_ln(const float* __restrict__ X, const float* __restrict__ g,
                     const float* __restrict__ b, float* __restrict__ node, int s) {
  int t = threadIdx.x & 63;
  int r = blockIdx.x * 4 + (threadIdx.x >> 6);  // 0..4095
  float4 x = ((const float4*)(X + (size_t)r * 256))[t];
  float sm = x.x + x.y + x.z + x.w;
  float sq = x.x * x.x + x.y * x.y + x.z * x.z + x.w * x.w;
  #pragma unroll
  for (int o = 1; o < 64; o <<= 1) { sm += __shfl_xor(sm, o); sq += __shfl_xor(sq, o); }
  float mu  = sm * (1.f / 256.f);
  float var = sq * (1.f / 256.f) - mu * mu;
  float rs  = rsqrtf(var + 1e-5f);
  float4 gv = ((const float4*)g)[t], bv = ((const float4*)b)[t];
  float4 o4;
  o4.x = (x.x - mu) * rs * gv.x + bv.x;
  o4.y = (x.y - mu) * rs * gv.y + bv.y;
  o4.z = (x.z - mu) * rs * gv.z + bv.z;
  o4.w = (x.w - mu) * rs * gv.w + bv.w;
  ((float4*)(node + (size_t)(s + r) * 256))[t] = o4;
}

extern "C" void kernel_launch(void* const* d_in, const int* in_sizes, int n_in,
                              void* d_out, int out_size, void* d_ws, size_t ws_size,
                              hipStream_t stream) {
  const int*   x_edges    = (const int*)d_in[1];
  const int*   y_edges    = (const int*)d_in[2];
  const float* input_embd = (const float*)d_in[3];
  const float* W_in       = (const float*)d_in[4];
  const float* b_in       = (const float*)d_in[5];
  const float* W_hid      = (const float*)d_in[6];
  const float* b_hid      = (const float*)d_in[7];
  const float* W_out      = (const float*)d_in[8];
  const float* b_out      = (const float*)d_in[9];
  const float* ln_g       = (const float*)d_in[10];
  const float* ln_b       = (const float*)d_in[11];
  float* node = (float*)d_out;

  char* ws = (char*)d_ws;
  bf16* WtIn  = (bf16*)(ws);                                   // 1024x512
  bf16* WtHid = (bf16*)(ws + (size_t)1048576);                 // 8x1024x1024
  bf16* WtOut = (bf16*)(ws + (size_t)17825792);                // 256x1024
  bf16* H0    = (bf16*)(ws + (size_t)18350080);                // 4096x512
  bf16* HA    = (bf16*)(ws + (size_t)22544384);                // 4096x1024
  bf16* HB    = (bf16*)(ws + (size_t)30932992);                // 4096x1024
  float* OutF = (float*)HB;                                    // reuse (4096x256 f32)

  // node rows 0..65 = input embeddings
  k_copy_inputs<<<dim3(66), dim3(64), 0, stream>>>(input_embd, node);

  // all weight transposes in one dispatch
  k_transpose_all<<<dim3(32, 32, 10), dim3(32, 8), 0, stream>>>(W_in, W_hid, W_out, WtIn, WtHid, WtOut);

  for (int l = 0; l < N_LEVELS; ++l) {
    int s = N_INPUTS + l * LVL;
    k_not_gather<<<dim3((NPL + APL) / 4), dim3(256), 0, stream>>>(x_edges, y_edges, node, H0, s);

    // MLP: 64x64 tiles -> 1024 blocks (4/CU) TLP probe
    k_gemm<64, 64, 4, true, true><<<dim3(64, 16), dim3(256), 0, stream>>>(H0, WtIn, b_in, HA, 4096, 1024, 512);
    const bf16* src = HA; bf16* dst = HB;
    for (int i = 0; i < 8; ++i) {
      k_gemm<64, 64, 4, true, true><<<dim3(64, 16), dim3(256), 0, stream>>>(
          src, WtHid + (size_t)i * 1024 * 1024, b_hid + i * 1024, dst, 4096, 1024, 1024);
      const bf16* tmp = src; src = dst; dst = (bf16*)tmp;
    }
    // src == HA here; fp32 MLP output into OutF (= HB space, no longer needed)
    k_gemm<64, 64, 2, false, false><<<dim3(64, 4), dim3(256), 0, stream>>>(src, WtOut, b_out, OutF, 4096, 256, 1024);

    k_ln<<<dim3(APL / 4), dim3(256), 0, stream>>>(OutF, ln_g, ln_b, node, s);
  }
}

// Round 15
// 978.131 us; speedup vs baseline: 1.1073x; 1.1036x over previous
//
#include <hip/hip_runtime.h>
#include <hip/hip_bf16.h>
#include <stdint.h>

#define N_EMBD    256
#define N_INPUTS  66
#define N_LEVELS  8
#define APL       4096
#define NPL       2048
#define LVL       6144
#define N_HID     1024

typedef __hip_bfloat16 bf16;
typedef __attribute__((ext_vector_type(8))) short short8;
typedef __attribute__((ext_vector_type(4))) float f32x4;

static __device__ __forceinline__ unsigned short f2b(float f) {
  bf16 h = __float2bfloat16(f);
  return *reinterpret_cast<unsigned short*>(&h);
}

// ---------------- input copy: rows 0..65 of node table ----------------
__global__ void k_copy_inputs(const float* __restrict__ in, float* __restrict__ out) {
  int r = blockIdx.x, t = threadIdx.x;  // 66 blocks x 64 threads
  ((float4*)(out + (size_t)r * 256))[t] = ((const float4*)(in + (size_t)r * 256))[t];
}

// ---------------- ALL weight transposes in ONE dispatch ----------------
__global__ void k_transpose_all(const float* __restrict__ W_in, const float* __restrict__ W_hid,
                                const float* __restrict__ W_out,
                                bf16* __restrict__ WtIn, bf16* __restrict__ WtHid,
                                bf16* __restrict__ WtOut) {
  __shared__ float t[32][33];
  int z = blockIdx.z;
  const float* in; bf16* out; int K, N;
  if (z == 0)      { in = W_in;  out = WtIn;  K = 512;  N = 1024; }
  else if (z <= 8) { in = W_hid + (size_t)(z - 1) * 1024 * 1024; out = WtHid + (size_t)(z - 1) * 1024 * 1024; K = 1024; N = 1024; }
  else             { in = W_out; out = WtOut; K = 1024; N = 256; }
  int n0 = blockIdx.x * 32, k0 = blockIdx.y * 32;
  if (n0 >= N || k0 >= K) return;
  int tx = threadIdx.x, ty = threadIdx.y;
  #pragma unroll
  for (int j = 0; j < 32; j += 8)
    t[ty + j][tx] = in[(size_t)(k0 + ty + j) * N + n0 + tx];
  __syncthreads();
  #pragma unroll
  for (int j = 0; j < 32; j += 8)
    out[(size_t)(n0 + ty + j) * K + k0 + tx] = __float2bfloat16(t[tx][ty + j]);
}

// ---------------- fused NOT + gather, 256-thread blocks (4 items each) ----------------
__global__ void k_not_gather(const int* __restrict__ xe, const int* __restrict__ ye,
                             float* __restrict__ node, bf16* __restrict__ H0, int s) {
  int t = threadIdx.x & 63;
  int b = blockIdx.x * 4 + (threadIdx.x >> 6);  // 0..6143
  if (b < NPL) {
    int dst = s + APL + b;
    int src = xe[dst];
    float4 v = ((const float4*)(node + (size_t)src * 256))[t];
    float4 o; o.x = -v.x; o.y = -v.y; o.z = -v.z; o.w = -v.w;
    ((float4*)(node + (size_t)dst * 256))[t] = o;
  } else {
    int r = b - NPL;
    int xa = xe[s + r], ya = ye[s + r];
    float4 vx = ((const float4*)(node + (size_t)xa * 256))[t];
    float4 vy = ((const float4*)(node + (size_t)ya * 256))[t];
    ushort4 ox, oy;
    ox.x = f2b(vx.x); ox.y = f2b(vx.y); ox.z = f2b(vx.z); ox.w = f2b(vx.w);
    oy.x = f2b(vy.x); oy.y = f2b(vy.y); oy.z = f2b(vy.z); oy.w = f2b(vy.w);
    bf16* hr = H0 + (size_t)r * 512;
    ((ushort4*)hr)[t] = ox;
    ((ushort4*)(hr + 256))[t] = oy;
  }
}

// ---------------- BIG GEMM: 512 threads (8 waves, 2/SIMD), 128x128 tile ----------------
// Combines R4's wave-occupancy (2 waves/SIMD) with R13's proven 4-buffer 3-deep
// counted-vmcnt rotation. 8 waves as 2x4 -> wave tile 64x32 (MT=4,NT=2).
// LDS 4 x 32KB = 128KB, 1 block/CU. LOADS=4/thread/STAGE -> steady vmcnt(8).
// Stage issued after entry barrier into buffer freed at previous exit barrier
// (R13 skeleton, refcheck-proven race-safe). Same MFMA K-order -> bit-identical.
// global_load_lds width 16, XOR-swizzle on global SOURCE + on ds_read (rule #21).
template<bool RELU, bool BF16OUT>
__global__ __launch_bounds__(512, 2)
void k_gemm512(const bf16* __restrict__ A, const bf16* __restrict__ Bt,
               const float* __restrict__ bias, void* __restrict__ Cout,
               int M, int N, int K) {
  constexpr int MT = 4, NT = 2;          // wave tile 64x32
  constexpr int AIT = 2, BIT = 2;        // staging iters per thread (512 thr)
  constexpr int ABYTES = 128 * 128;      // 128 rows x 64 bf16 = 16 KB
  constexpr int BUF = 2 * ABYTES;        // A + B = 32 KB
  __shared__ __align__(16) char smem[4 * BUF];  // 128 KB

  const int tid  = threadIdx.x;
  const int lane = tid & 63;
  const int w    = tid >> 6;             // 0..7
  const int wm   = w >> 2, wn = w & 3;   // 2 x 4 wave grid
  const int m0 = blockIdx.x * 128;
  const int n0 = blockIdx.y * 128;

  // running global source pointers (swizzled), advanced +64 per STAGE
  const bf16* gA[AIT];
  const bf16* gB[BIT];
  #pragma unroll
  for (int it = 0; it < AIT; ++it) {
    int ci = it * 512 + tid;             // chunk 0..1023
    int r = ci >> 3, g = ci & 7, gs = g ^ (r & 7);
    gA[it] = A + (size_t)(m0 + r) * K + gs * 8;
  }
  #pragma unroll
  for (int it = 0; it < BIT; ++it) {
    int ci = it * 512 + tid;
    int r = ci >> 3, g = ci & 7, gs = g ^ (r & 7);
    gB[it] = Bt + (size_t)(n0 + r) * K + gs * 8;
  }

  // precomputed swizzled ds_read byte offsets
  int aoff[2][MT], boff[2][NT];
  #pragma unroll
  for (int kk = 0; kk < 2; ++kk) {
    #pragma unroll
    for (int mt = 0; mt < MT; ++mt) {
      int row = wm * 64 + mt * 16 + (lane & 15);
      int g = kk * 4 + (lane >> 4);
      aoff[kk][mt] = row * 128 + ((g ^ (row & 7)) * 16);
    }
    #pragma unroll
    for (int nt = 0; nt < NT; ++nt) {
      int row = wn * 32 + nt * 16 + (lane & 15);
      int g = kk * 4 + (lane >> 4);
      boff[kk][nt] = ABYTES + row * 128 + ((g ^ (row & 7)) * 16);
    }
  }

  f32x4 acc[MT][NT] = {};

  auto STAGE = [&](auto bufsel) {
    constexpr int BS = decltype(bufsel)::value;
    char* sA = smem + BS * BUF;
    char* sB = sA + ABYTES;
    #pragma unroll
    for (int it = 0; it < AIT; ++it) {
      __builtin_amdgcn_global_load_lds((const __attribute__((address_space(1))) void*)gA[it],
                                       (__attribute__((address_space(3))) void*)(sA + (it * 512 + w * 64) * 16),
                                       16, 0, 0);
      gA[it] += 64;
    }
    #pragma unroll
    for (int it = 0; it < BIT; ++it) {
      __builtin_amdgcn_global_load_lds((const __attribute__((address_space(1))) void*)gB[it],
                                       (__attribute__((address_space(3))) void*)(sB + (it * 512 + w * 64) * 16),
                                       16, 0, 0);
      gB[it] += 64;
    }
  };

  auto COMPUTE = [&](auto bufsel) {
    constexpr int BS = decltype(bufsel)::value;
    char* base = smem + BS * BUF;
    #pragma unroll
    for (int kk = 0; kk < 2; ++kk) {
      short8 af[MT], bfr[NT];
      #pragma unroll
      for (int mt = 0; mt < MT; ++mt)
        af[mt] = *(const short8*)(base + aoff[kk][mt]);
      #pragma unroll
      for (int nt = 0; nt < NT; ++nt)
        bfr[nt] = *(const short8*)(base + boff[kk][nt]);
      #pragma unroll
      for (int mt = 0; mt < MT; ++mt)
        #pragma unroll
        for (int nt = 0; nt < NT; ++nt)
          acc[mt][nt] = __builtin_amdgcn_mfma_f32_16x16x32_bf16(af[mt], bfr[nt], acc[mt][nt], 0, 0, 0);
    }
  };

  constexpr auto B0 = std::integral_constant<int, 0>{};
  constexpr auto B1 = std::integral_constant<int, 1>{};
  constexpr auto B2 = std::integral_constant<int, 2>{};
  constexpr auto B3 = std::integral_constant<int, 3>{};

  const int nK = K >> 6;  // 8 or 16: divisible by 4

  auto SUBSTEP = [&](int t, auto cbuf, auto sbuf) {
    int rem = nK - 1 - t;
    if (rem >= 2)      asm volatile("s_waitcnt vmcnt(8)" ::: "memory");
    else if (rem == 1) asm volatile("s_waitcnt vmcnt(4)" ::: "memory");
    else               asm volatile("s_waitcnt vmcnt(0)" ::: "memory");
    __builtin_amdgcn_s_barrier();          // all waves: batch t landed
    if (t + 3 < nK) STAGE(sbuf);           // into buffer freed at t-1's exit barrier
    COMPUTE(cbuf);
    __builtin_amdgcn_s_barrier();          // all waves done reading cbuf
  };

  STAGE(B0); STAGE(B1); STAGE(B2);         // batches 0,1,2

  for (int t4 = 0; t4 < nK; t4 += 4) {
    SUBSTEP(t4 + 0, B0, B3);
    SUBSTEP(t4 + 1, B1, B0);
    SUBSTEP(t4 + 2, B2, B1);
    SUBSTEP(t4 + 3, B3, B2);
  }

  // epilogue: bias + optional relu
  #pragma unroll
  for (int nt = 0; nt < NT; ++nt) {
    int col = n0 + wn * 32 + nt * 16 + (lane & 15);
    float bv = bias[col];
    #pragma unroll
    for (int mt = 0; mt < MT; ++mt) {
      int rbase = m0 + wm * 64 + mt * 16 + (lane >> 4) * 4;
      #pragma unroll
      for (int r = 0; r < 4; ++r) {
        float v = acc[mt][nt][r] + bv;
        if (RELU) v = fmaxf(v, 0.f);
        if (BF16OUT)
          ((unsigned short*)Cout)[(size_t)(rbase + r) * N + col] = f2b(v);
        else
          ((float*)Cout)[(size_t)(rbase + r) * N + col] = v;
      }
    }
  }
}

// ---------------- small GEMM (out layer): R7 proven 64x64 structure ----------------
template<int BM, int BN, bool RELU, bool BF16OUT>
__global__ __launch_bounds__(256, 2)
void k_gemm(const bf16* __restrict__ A, const bf16* __restrict__ Bt,
            const float* __restrict__ bias, void* __restrict__ Cout,
            int M, int N, int K) {
  constexpr int MT = BM / 32;
  constexpr int NT = BN / 32;
  constexpr int AIT = BM / 32;
  constexpr int BIT = BN / 32;
  constexpr int ABYTES = BM * 128;
  constexpr int BBYTES = BN * 128;
  constexpr int BUF = ABYTES + BBYTES;
  constexpr int LOADS = AIT + BIT;
  __shared__ __align__(16) char smem[2 * BUF];

  const int tid  = threadIdx.x;
  const int lane = tid & 63;
  const int w    = tid >> 6;
  const int wm   = w >> 1, wn = w & 1;
  const int m0 = blockIdx.x * BM;
  const int n0 = blockIdx.y * BN;

  const bf16* gA[AIT];
  const bf16* gB[BIT];
  #pragma unroll
  for (int it = 0; it < AIT; ++it) {
    int ci = it * 256 + tid;
    int r = ci >> 3, g = ci & 7, gs = g ^ (r & 7);
    gA[it] = A + (size_t)(m0 + r) * K + gs * 8;
  }
  #pragma unroll
  for (int it = 0; it < BIT; ++it) {
    int ci = it * 256 + tid;
    int r = ci >> 3, g = ci & 7, gs = g ^ (r & 7);
    gB[it] = Bt + (size_t)(n0 + r) * K + gs * 8;
  }

  int aoff[2][MT], boff[2][NT];
  #pragma unroll
  for (int kk = 0; kk < 2; ++kk) {
    #pragma unroll
    for (int mt = 0; mt < MT; ++mt) {
      int row = wm * (BM / 2) + mt * 16 + (lane & 15);
      int g = kk * 4 + (lane >> 4);
      aoff[kk][mt] = row * 128 + ((g ^ (row & 7)) * 16);
    }
    #pragma unroll
    for (int nt = 0; nt < NT; ++nt) {
      int row = wn * (BN / 2) + nt * 16 + (lane & 15);
      int g = kk * 4 + (lane >> 4);
      boff[kk][nt] = ABYTES + row * 128 + ((g ^ (row & 7)) * 16);
    }
  }

  f32x4 acc[MT][NT] = {};

  auto STAGE = [&](auto bufsel) {
    constexpr int BS = decltype(bufsel)::value;
    char* sA = smem + BS * BUF;
    char* sB = sA + ABYTES;
    #pragma unroll
    for (int it = 0; it < AIT; ++it) {
      __builtin_amdgcn_global_load_lds((const __attribute__((address_space(1))) void*)gA[it],
                                       (__attribute__((address_space(3))) void*)(sA + (it * 256 + w * 64) * 16),
                                       16, 0, 0);
      gA[it] += 64;
    }
    #pragma unroll
    for (int it = 0; it < BIT; ++it) {
      __builtin_amdgcn_global_load_lds((const __attribute__((address_space(1))) void*)gB[it],
                                       (__attribute__((address_space(3))) void*)(sB + (it * 256 + w * 64) * 16),
                                       16, 0, 0);
      gB[it] += 64;
    }
  };

  auto COMPUTE = [&](auto bufsel) {
    constexpr int BS = decltype(bufsel)::value;
    char* base = smem + BS * BUF;
    #pragma unroll
    for (int kk = 0; kk < 2; ++kk) {
      short8 af[MT], bfr[NT];
      #pragma unroll
      for (int mt = 0; mt < MT; ++mt)
        af[mt] = *(const short8*)(base + aoff[kk][mt]);
      #pragma unroll
      for (int nt = 0; nt < NT; ++nt)
        bfr[nt] = *(const short8*)(base + boff[kk][nt]);
      #pragma unroll
      for (int mt = 0; mt < MT; ++mt)
        #pragma unroll
        for (int nt = 0; nt < NT; ++nt)
          acc[mt][nt] = __builtin_amdgcn_mfma_f32_16x16x32_bf16(af[mt], bfr[nt], acc[mt][nt], 0, 0, 0);
    }
  };

  auto WAITC = [&](auto n) {
    constexpr int NW = decltype(n)::value;
    if constexpr (NW == 6)      asm volatile("s_waitcnt vmcnt(6)" ::: "memory");
    else if constexpr (NW == 4) asm volatile("s_waitcnt vmcnt(4)" ::: "memory");
    else                        asm volatile("s_waitcnt vmcnt(0)" ::: "memory");
  };
  constexpr auto C0 = std::integral_constant<int, 0>{};
  constexpr auto C1 = std::integral_constant<int, 1>{};
  constexpr auto CL = std::integral_constant<int, LOADS>{};

  const int nK = K >> 6;
  STAGE(C0);
  STAGE(C1);

  for (int ks2 = 0; ks2 < nK; ks2 += 2) {
    WAITC(CL);
    __builtin_amdgcn_s_barrier();
    COMPUTE(C0);
    __builtin_amdgcn_s_barrier();
    if (ks2 + 2 < nK) STAGE(C0);

    if (ks2 + 2 < nK) WAITC(CL); else WAITC(C0);
    __builtin_amdgcn_s_barrier();
    COMPUTE(C1);
    __builtin_amdgcn_s_barrier();
    if (ks2 + 3 < nK) STAGE(C1);
  }

  #pragma unroll
  for (int nt = 0; nt < NT; ++nt) {
    int col = n0 + wn * (BN / 2) + nt * 16 + (lane & 15);
    float bv = bias[col];
    #pragma unroll
    for (int mt = 0; mt < MT; ++mt) {
      int rbase = m0 + wm * (BM / 2) + mt * 16 + (lane >> 4) * 4;
      #pragma unroll
      for (int r = 0; r < 4; ++r) {
        float v = acc[mt][nt][r] + bv;
        if (RELU) v = fmaxf(v, 0.f);
        if (BF16OUT)
          ((unsigned short*)Cout)[(size_t)(rbase + r) * N + col] = f2b(v);
        else
          ((float*)Cout)[(size_t)(rbase + r) * N + col] = v;
      }
    }
  }
}

// ---------------- LayerNorm, 256-thread blocks (4 rows each) ----------------
__global__ void k_ln(const float* __restrict__ X, const float* __restrict__ g,
                     const float* __restrict__ b, float* __restrict__ node, int s) {
  int t = threadIdx.x & 63;
  int r = blockIdx.x * 4 + (threadIdx.x >> 6);  // 0..4095
  float4 x = ((const float4*)(X + (size_t)r * 256))[t];
  float sm = x.x + x.y + x.z + x.w;
  float sq = x.x * x.x + x.y * x.y + x.z * x.z + x.w * x.w;
  #pragma unroll
  for (int o = 1; o < 64; o <<= 1) { sm += __shfl_xor(sm, o); sq += __shfl_xor(sq, o); }
  float mu  = sm * (1.f / 256.f);
  float var = sq * (1.f / 256.f) - mu * mu;
  float rs  = rsqrtf(var + 1e-5f);
  float4 gv = ((const float4*)g)[t], bv = ((const float4*)b)[t];
  float4 o4;
  o4.x = (x.x - mu) * rs * gv.x + bv.x;
  o4.y = (x.y - mu) * rs * gv.y + bv.y;
  o4.z = (x.z - mu) * rs * gv.z + bv.z;
  o4.w = (x.w - mu) * rs * gv.w + bv.w;
  ((float4*)(node + (size_t)(s + r) * 256))[t] = o4;
}

extern "C" void kernel_launch(void* const* d_in, const int* in_sizes, int n_in,
                              void* d_out, int out_size, void* d_ws, size_t ws_size,
                              hipStream_t stream) {
  const int*   x_edges    = (const int*)d_in[1];
  const int*   y_edges    = (const int*)d_in[2];
  const float* input_embd = (const float*)d_in[3];
  const float* W_in       = (const float*)d_in[4];
  const float* b_in       = (const float*)d_in[5];
  const float* W_hid      = (const float*)d_in[6];
  const float* b_hid      = (const float*)d_in[7];
  const float* W_out      = (const float*)d_in[8];
  const float* b_out      = (const float*)d_in[9];
  const float* ln_g       = (const float*)d_in[10];
  const float* ln_b       = (const float*)d_in[11];
  float* node = (float*)d_out;

  char* ws = (char*)d_ws;
  bf16* WtIn  = (bf16*)(ws);                                   // 1024x512
  bf16* WtHid = (bf16*)(ws + (size_t)1048576);                 // 8x1024x1024
  bf16* WtOut = (bf16*)(ws + (size_t)17825792);                // 256x1024
  bf16* H0    = (bf16*)(ws + (size_t)18350080);                // 4096x512
  bf16* HA    = (bf16*)(ws + (size_t)22544384);                // 4096x1024
  bf16* HB    = (bf16*)(ws + (size_t)30932992);                // 4096x1024
  float* OutF = (float*)HB;                                    // reuse (4096x256 f32)

  // node rows 0..65 = input embeddings
  k_copy_inputs<<<dim3(66), dim3(64), 0, stream>>>(input_embd, node);

  // all weight transposes in one dispatch
  k_transpose_all<<<dim3(32, 32, 10), dim3(32, 8), 0, stream>>>(W_in, W_hid, W_out, WtIn, WtHid, WtOut);

  for (int l = 0; l < N_LEVELS; ++l) {
    int s = N_INPUTS + l * LVL;
    k_not_gather<<<dim3((NPL + APL) / 4), dim3(256), 0, stream>>>(x_edges, y_edges, node, H0, s);

    // MLP: 512-thread 128x128 tiles -> 256 blocks, 8 waves (2/SIMD), 4-buf 3-deep
    k_gemm512<true, true><<<dim3(32, 8), dim3(512), 0, stream>>>(H0, WtIn, b_in, HA, 4096, 1024, 512);
    const bf16* src = HA; bf16* dst = HB;
    for (int i = 0; i < 8; ++i) {
      k_gemm512<true, true><<<dim3(32, 8), dim3(512), 0, stream>>>(
          src, WtHid + (size_t)i * 1024 * 1024, b_hid + i * 1024, dst, 4096, 1024, 1024);
      const bf16* tmp = src; src = dst; dst = (bf16*)tmp;
    }
    // src == HA here; fp32 MLP output into OutF (= HB space, no longer needed)
    k_gemm<64, 64, false, false><<<dim3(64, 4), dim3(256), 0, stream>>>(src, WtOut, b_out, OutF, 4096, 256, 1024);

    k_ln<<<dim3(APL / 4), dim3(256), 0, stream>>>(OutF, ln_g, ln_b, node, s);
  }
}

// Round 16
// 942.802 us; speedup vs baseline: 1.1488x; 1.0375x over previous
//
#include <hip/hip_runtime.h>
#include <hip/hip_bf16.h>
#include <stdint.h>

#define N_EMBD    256
#define N_INPUTS  66
#define N_LEVELS  8
#define APL       4096
#define NPL       2048
#define LVL       6144
#define N_HID     1024

typedef __hip_bfloat16 bf16;
typedef __attribute__((ext_vector_type(8))) short short8;
typedef __attribute__((ext_vector_type(4))) float f32x4;

static __device__ __forceinline__ unsigned short f2b(float f) {
  bf16 h = __float2bfloat16(f);
  return *reinterpret_cast<unsigned short*>(&h);
}

// ---------------- input copy: rows 0..65 of node table ----------------
__global__ void k_copy_inputs(const float* __restrict__ in, float* __restrict__ out) {
  int r = blockIdx.x, t = threadIdx.x;  // 66 blocks x 64 threads
  ((float4*)(out + (size_t)r * 256))[t] = ((const float4*)(in + (size_t)r * 256))[t];
}

// ---------------- ALL weight transposes in ONE dispatch ----------------
__global__ void k_transpose_all(const float* __restrict__ W_in, const float* __restrict__ W_hid,
                                const float* __restrict__ W_out,
                                bf16* __restrict__ WtIn, bf16* __restrict__ WtHid,
                                bf16* __restrict__ WtOut) {
  __shared__ float t[32][33];
  int z = blockIdx.z;
  const float* in; bf16* out; int K, N;
  if (z == 0)      { in = W_in;  out = WtIn;  K = 512;  N = 1024; }
  else if (z <= 8) { in = W_hid + (size_t)(z - 1) * 1024 * 1024; out = WtHid + (size_t)(z - 1) * 1024 * 1024; K = 1024; N = 1024; }
  else             { in = W_out; out = WtOut; K = 1024; N = 256; }
  int n0 = blockIdx.x * 32, k0 = blockIdx.y * 32;
  if (n0 >= N || k0 >= K) return;
  int tx = threadIdx.x, ty = threadIdx.y;
  #pragma unroll
  for (int j = 0; j < 32; j += 8)
    t[ty + j][tx] = in[(size_t)(k0 + ty + j) * N + n0 + tx];
  __syncthreads();
  #pragma unroll
  for (int j = 0; j < 32; j += 8)
    out[(size_t)(n0 + ty + j) * K + k0 + tx] = __float2bfloat16(t[tx][ty + j]);
}

// ---------------- fused NOT + gather, 256-thread blocks (4 items each) ----------------
__global__ void k_not_gather(const int* __restrict__ xe, const int* __restrict__ ye,
                             float* __restrict__ node, bf16* __restrict__ H0, int s) {
  int t = threadIdx.x & 63;
  int b = blockIdx.x * 4 + (threadIdx.x >> 6);  // 0..6143
  if (b < NPL) {
    int dst = s + APL + b;
    int src = xe[dst];
    float4 v = ((const float4*)(node + (size_t)src * 256))[t];
    float4 o; o.x = -v.x; o.y = -v.y; o.z = -v.z; o.w = -v.w;
    ((float4*)(node + (size_t)dst * 256))[t] = o;
  } else {
    int r = b - NPL;
    int xa = xe[s + r], ya = ye[s + r];
    float4 vx = ((const float4*)(node + (size_t)xa * 256))[t];
    float4 vy = ((const float4*)(node + (size_t)ya * 256))[t];
    ushort4 ox, oy;
    ox.x = f2b(vx.x); ox.y = f2b(vx.y); ox.z = f2b(vx.z); ox.w = f2b(vx.w);
    oy.x = f2b(vy.x); oy.y = f2b(vy.y); oy.z = f2b(vy.z); oy.w = f2b(vy.w);
    bf16* hr = H0 + (size_t)r * 512;
    ((ushort4*)hr)[t] = ox;
    ((ushort4*)(hr + 256))[t] = oy;
  }
}

// ---------------- GEMM: C = act(A[MxK] @ B[KxN] + bias), Bt[N][K] ----------------
// R12 winner (128x64, 4 waves 2x2, 2 blocks/CU, counted vmcnt) + NEW: 3 LDS buffers,
// ONE barrier per K-step (T3-min shape). Stage of batch t+2 goes into buffer
// (t+2)%3 == (t-1)%3, whose readers (batch t-1 compute) all finished before their
// step-t entry barrier -> race-safe with no exit barrier. Each load batch now has
// TWO compute phases of latency cover (issued step t, waited step t+2).
// vmcnt: in flight at step-t entry <= {t, t+1} -> wait vmcnt(LOADS); tail -> 0.
// NK templated (8/16) -> full unroll, constant buffer selects.
// COMPUTE body and batch order unchanged -> bit-identical output.
// global_load_lds width 16, XOR-swizzle on global SOURCE + on ds_read (rule #21).
template<int BM, int BN, int NK, bool RELU, bool BF16OUT>
__global__ __launch_bounds__(256, 2)
void k_gemm(const bf16* __restrict__ A, const bf16* __restrict__ Bt,
            const float* __restrict__ bias, void* __restrict__ Cout,
            int M, int N, int K) {
  constexpr int MT = BM / 32;            // A-frags per wave (wave owns BM/2 rows)
  constexpr int NT = BN / 32;
  constexpr int AIT = BM / 32;           // A-load iters per STAGE
  constexpr int BIT = BN / 32;
  constexpr int ABYTES = BM * 128;       // BM rows x 64 bf16
  constexpr int BBYTES = BN * 128;
  constexpr int BUF = ABYTES + BBYTES;
  constexpr int LOADS = AIT + BIT;       // global_load_lds per thread per STAGE
  __shared__ __align__(16) char smem[3 * BUF];

  const int tid  = threadIdx.x;
  const int lane = tid & 63;
  const int w    = tid >> 6;
  const int wm   = w >> 1, wn = w & 1;
  const int m0 = blockIdx.x * BM;
  const int n0 = blockIdx.y * BN;

  // ---- running global source pointers (swizzled), advanced +64 per STAGE ----
  const bf16* gA[AIT];
  const bf16* gB[BIT];
  #pragma unroll
  for (int it = 0; it < AIT; ++it) {
    int ci = it * 256 + tid;
    int r = ci >> 3, g = ci & 7, gs = g ^ (r & 7);
    gA[it] = A + (size_t)(m0 + r) * K + gs * 8;
  }
  #pragma unroll
  for (int it = 0; it < BIT; ++it) {
    int ci = it * 256 + tid;
    int r = ci >> 3, g = ci & 7, gs = g ^ (r & 7);
    gB[it] = Bt + (size_t)(n0 + r) * K + gs * 8;
  }

  // ---- precomputed swizzled ds_read byte offsets (buffer-relative) ----
  int aoff[2][MT], boff[2][NT];
  #pragma unroll
  for (int kk = 0; kk < 2; ++kk) {
    #pragma unroll
    for (int mt = 0; mt < MT; ++mt) {
      int row = wm * (BM / 2) + mt * 16 + (lane & 15);
      int g = kk * 4 + (lane >> 4);
      aoff[kk][mt] = row * 128 + ((g ^ (row & 7)) * 16);
    }
    #pragma unroll
    for (int nt = 0; nt < NT; ++nt) {
      int row = wn * (BN / 2) + nt * 16 + (lane & 15);
      int g = kk * 4 + (lane >> 4);
      boff[kk][nt] = ABYTES + row * 128 + ((g ^ (row & 7)) * 16);
    }
  }

  f32x4 acc[MT][NT] = {};

  auto STAGE = [&](char* base) {
    char* sA = base;
    char* sB = base + ABYTES;
    #pragma unroll
    for (int it = 0; it < AIT; ++it) {
      __builtin_amdgcn_global_load_lds((const __attribute__((address_space(1))) void*)gA[it],
                                       (__attribute__((address_space(3))) void*)(sA + (it * 256 + w * 64) * 16),
                                       16, 0, 0);
      gA[it] += 64;
    }
    #pragma unroll
    for (int it = 0; it < BIT; ++it) {
      __builtin_amdgcn_global_load_lds((const __attribute__((address_space(1))) void*)gB[it],
                                       (__attribute__((address_space(3))) void*)(sB + (it * 256 + w * 64) * 16),
                                       16, 0, 0);
      gB[it] += 64;
    }
  };

  auto COMPUTE = [&](char* base) {
    #pragma unroll
    for (int kk = 0; kk < 2; ++kk) {
      short8 af[MT], bfr[NT];
      #pragma unroll
      for (int mt = 0; mt < MT; ++mt)
        af[mt] = *(const short8*)(base + aoff[kk][mt]);
      #pragma unroll
      for (int nt = 0; nt < NT; ++nt)
        bfr[nt] = *(const short8*)(base + boff[kk][nt]);
      #pragma unroll
      for (int mt = 0; mt < MT; ++mt)
        #pragma unroll
        for (int nt = 0; nt < NT; ++nt)
          acc[mt][nt] = __builtin_amdgcn_mfma_f32_16x16x32_bf16(af[mt], bfr[nt], acc[mt][nt], 0, 0, 0);
    }
  };

  // prologue: batch 0 -> buf0, batch 1 -> buf1
  STAGE(smem);
  STAGE(smem + BUF);

  #pragma unroll
  for (int t = 0; t < NK; ++t) {
    if (t < NK - 1) {
      if constexpr (LOADS == 6)      asm volatile("s_waitcnt vmcnt(6)" ::: "memory");
      else if constexpr (LOADS == 4) asm volatile("s_waitcnt vmcnt(4)" ::: "memory");
      else                           asm volatile("s_waitcnt vmcnt(0)" ::: "memory");
    } else {
      asm volatile("s_waitcnt vmcnt(0)" ::: "memory");
    }
    __builtin_amdgcn_s_barrier();           // batch t landed (all waves); buf (t-1)%3 free
    if (t + 2 < NK) STAGE(smem + ((t + 2) % 3) * BUF);  // batch t+2 into buf (t-1)%3
    COMPUTE(smem + (t % 3) * BUF);
  }

  // epilogue: bias + optional relu, bf16 or fp32 store
  #pragma unroll
  for (int nt = 0; nt < NT; ++nt) {
    int col = n0 + wn * (BN / 2) + nt * 16 + (lane & 15);
    float bv = bias[col];
    #pragma unroll
    for (int mt = 0; mt < MT; ++mt) {
      int rbase = m0 + wm * (BM / 2) + mt * 16 + (lane >> 4) * 4;
      #pragma unroll
      for (int r = 0; r < 4; ++r) {
        float v = acc[mt][nt][r] + bv;
        if (RELU) v = fmaxf(v, 0.f);
        if (BF16OUT)
          ((unsigned short*)Cout)[(size_t)(rbase + r) * N + col] = f2b(v);
        else
          ((float*)Cout)[(size_t)(rbase + r) * N + col] = v;
      }
    }
  }
}

// ---------------- LayerNorm, 256-thread blocks (4 rows each) ----------------
__global__ void k_ln(const float* __restrict__ X, const float* __restrict__ g,
                     const float* __restrict__ b, float* __restrict__ node, int s) {
  int t = threadIdx.x & 63;
  int r = blockIdx.x * 4 + (threadIdx.x >> 6);  // 0..4095
  float4 x = ((const float4*)(X + (size_t)r * 256))[t];
  float sm = x.x + x.y + x.z + x.w;
  float sq = x.x * x.x + x.y * x.y + x.z * x.z + x.w * x.w;
  #pragma unroll
  for (int o = 1; o < 64; o <<= 1) { sm += __shfl_xor(sm, o); sq += __shfl_xor(sq, o); }
  float mu  = sm * (1.f / 256.f);
  float var = sq * (1.f / 256.f) - mu * mu;
  float rs  = rsqrtf(var + 1e-5f);
  float4 gv = ((const float4*)g)[t], bv = ((const float4*)b)[t];
  float4 o4;
  o4.x = (x.x - mu) * rs * gv.x + bv.x;
  o4.y = (x.y - mu) * rs * gv.y + bv.y;
  o4.z = (x.z - mu) * rs * gv.z + bv.z;
  o4.w = (x.w - mu) * rs * gv.w + bv.w;
  ((float4*)(node + (size_t)(s + r) * 256))[t] = o4;
}

extern "C" void kernel_launch(void* const* d_in, const int* in_sizes, int n_in,
                              void* d_out, int out_size, void* d_ws, size_t ws_size,
                              hipStream_t stream) {
  const int*   x_edges    = (const int*)d_in[1];
  const int*   y_edges    = (const int*)d_in[2];
  const float* input_embd = (const float*)d_in[3];
  const float* W_in       = (const float*)d_in[4];
  const float* b_in       = (const float*)d_in[5];
  const float* W_hid      = (const float*)d_in[6];
  const float* b_hid      = (const float*)d_in[7];
  const float* W_out      = (const float*)d_in[8];
  const float* b_out      = (const float*)d_in[9];
  const float* ln_g       = (const float*)d_in[10];
  const float* ln_b       = (const float*)d_in[11];
  float* node = (float*)d_out;

  char* ws = (char*)d_ws;
  bf16* WtIn  = (bf16*)(ws);                                   // 1024x512
  bf16* WtHid = (bf16*)(ws + (size_t)1048576);                 // 8x1024x1024
  bf16* WtOut = (bf16*)(ws + (size_t)17825792);                // 256x1024
  bf16* H0    = (bf16*)(ws + (size_t)18350080);                // 4096x512
  bf16* HA    = (bf16*)(ws + (size_t)22544384);                // 4096x1024
  bf16* HB    = (bf16*)(ws + (size_t)30932992);                // 4096x1024
  float* OutF = (float*)HB;                                    // reuse (4096x256 f32)

  // node rows 0..65 = input embeddings
  k_copy_inputs<<<dim3(66), dim3(64), 0, stream>>>(input_embd, node);

  // all weight transposes in one dispatch
  k_transpose_all<<<dim3(32, 32, 10), dim3(32, 8), 0, stream>>>(W_in, W_hid, W_out, WtIn, WtHid, WtOut);

  for (int l = 0; l < N_LEVELS; ++l) {
    int s = N_INPUTS + l * LVL;
    k_not_gather<<<dim3((NPL + APL) / 4), dim3(256), 0, stream>>>(x_edges, y_edges, node, H0, s);

    // MLP: 128x64 tiles -> 512 blocks (2/CU), 3-buffer 1-barrier/K-step pipeline
    k_gemm<128, 64, 8, true, true><<<dim3(32, 16), dim3(256), 0, stream>>>(H0, WtIn, b_in, HA, 4096, 1024, 512);
    const bf16* src = HA; bf16* dst = HB;
    for (int i = 0; i < 8; ++i) {
      k_gemm<128, 64, 16, true, true><<<dim3(32, 16), dim3(256), 0, stream>>>(
          src, WtHid + (size_t)i * 1024 * 1024, b_hid + i * 1024, dst, 4096, 1024, 1024);
      const bf16* tmp = src; src = dst; dst = (bf16*)tmp;
    }
    // src == HA here; fp32 MLP output into OutF (= HB space, no longer needed)
    k_gemm<64, 64, 16, false, false><<<dim3(64, 4), dim3(256), 0, stream>>>(src, WtOut, b_out, OutF, 4096, 256, 1024);

    k_ln<<<dim3(APL / 4), dim3(256), 0, stream>>>(OutF, ln_g, ln_b, node, s);
  }
}